// Round 6
// baseline (652.394 us; speedup 1.0000x reference)
//
#include <hip/hip_runtime.h>
#include <stdint.h>

#define B_ 1024
#define Q_ 65536
#define D_ 512
#define MT 128
#define NT 128
#define BK 64
#define NSPLIT 128
#define NCHUNK (Q_ / NSPLIT)   // 512
#define NTILES (NCHUNK / NT)   // 4
#define KITERS (D_ / BK)       // 8
#define MMAX 8192              // capacity of compacted masked-row arrays
#define MTILES (MMAX / NT)     // 64

#define SCALE32 32.0f
#define C32 46.16624130844683f   // 32 * log2(e)

// ---- workspace layout (bytes) ----
// [0,64)     : ce_acc f32 | neg_acc f32 | npos | nneg | done | mcnt
// [64)       : zdelta f32 [1024]  (s1 - s0 per row)                 (4 KB)
// [8 KB)     : main Z partials f32 [row][128 splits]                (512 KB)
// [1 MB)     : main top-10 lists  [row][128 splits][10] f32         (5 MB)
// [6 MB)     : masked top-10 lists [half][row][64 tiles][10] f32    (5.24 MB)
// [12 MB)    : p bf16 (1 MB)
// [16 MB)    : queue[0] bf16 (64 MB)
// [80 MB)    : qmc bf16 (8192x512, zero-padded)  (8 MB)
// [88 MB)    : wmc bf16 (8192x512, zero-padded)  (8 MB)   -> 96 MB total
#define WS_ZDELTA 64
#define WS_LSE    8192
#define WS_TOPK   (1u << 20)
#define WS_TOPKM  (6u << 20)
#define WS_PBF    (12u << 20)
#define WS_QBF0   (16u << 20)
#define WS_QMC    (80u << 20)
#define WS_WMC    (88u << 20)

// ---- LDS: staging sA[0,16K) sB[16K,32K), 16B-XOR swizzle.
// compact tile (32 rows x 128 cols bf16, stride 136 for bank spread) aliases sA.
#define SA_OFF 0
#define SB_OFF 16384
#define CPSTRIDE 136

typedef __attribute__((ext_vector_type(8))) short short8;
typedef __attribute__((ext_vector_type(4))) short short4v;
typedef __attribute__((ext_vector_type(4))) float f32x4;

__device__ __forceinline__ unsigned short f2bf(float x) {
  union { float f; uint32_t u; } v; v.f = x;
  uint32_t r = v.u + 0x7fffu + ((v.u >> 16) & 1u);   // RNE
  return (unsigned short)(r >> 16);
}

__device__ __forceinline__ float bf2f(short u) {
  union { uint32_t i; float f; } v;
  v.i = ((uint32_t)(unsigned short)u) << 16;
  return v.f;
}

__device__ __forceinline__ void async16(void* lds, const void* g) {
  void* gg = (void*)g;
  __builtin_amdgcn_global_load_lds(
      (__attribute__((address_space(1))) unsigned int*)gg,
      (__attribute__((address_space(3))) unsigned int*)lds,
      16, 0, 0);
}

__device__ __forceinline__ void tkins(float v,
    float& t0, float& t1, float& t2, float& t3, float& t4,
    float& t5, float& t6, float& t7, float& t8, float& t9) {
  if (v > t9) {
    t9 = (v > t8) ? t8 : v;
    t8 = (v > t8) ? ((v > t7) ? t7 : v) : t8;
    t7 = (v > t7) ? ((v > t6) ? t6 : v) : t7;
    t6 = (v > t6) ? ((v > t5) ? t5 : v) : t6;
    t5 = (v > t5) ? ((v > t4) ? t4 : v) : t5;
    t4 = (v > t4) ? ((v > t3) ? t3 : v) : t4;
    t3 = (v > t3) ? ((v > t2) ? t2 : v) : t3;
    t2 = (v > t2) ? ((v > t1) ? t1 : v) : t2;
    t1 = (v > t1) ? ((v > t0) ? t0 : v) : t1;
    t0 = (v > t0) ? v : t0;
  }
}
#define TKA(v, a) tkins((v), a[0], a[1], a[2], a[3], a[4], a[5], a[6], a[7], a[8], a[9])

// converter: q0 -> qbf0; masked rows compact-append to {qmc, wmc}; p -> pbf
__global__ void cvt_all(const float* __restrict__ q, const float* __restrict__ p,
                        const float* __restrict__ mask,
                        unsigned short* __restrict__ qbf0,
                        unsigned short* __restrict__ pbf,
                        unsigned short* __restrict__ qmc,
                        unsigned short* __restrict__ wmc,
                        int* __restrict__ wsi) {
  const int wv = threadIdx.x >> 6;
  const int lane = threadIdx.x & 63;
  const int b = blockIdx.x;
  if (b < Q_ / 4) {
    const int row = b * 4 + wv;
    const float* q0r = q + (size_t)row * D_ + lane * 8;
    float4 a = ((const float4*)q0r)[0];
    float4 bb = ((const float4*)q0r)[1];
    short8 o;
    o[0] = (short)f2bf(a.x); o[1] = (short)f2bf(a.y);
    o[2] = (short)f2bf(a.z); o[3] = (short)f2bf(a.w);
    o[4] = (short)f2bf(bb.x); o[5] = (short)f2bf(bb.y);
    o[6] = (short)f2bf(bb.z); o[7] = (short)f2bf(bb.w);
    *(short8*)(qbf0 + (size_t)row * D_ + lane * 8) = o;
    float m = mask[row];
    if (m != 0.0f) {      // wave-uniform; ~10% of rows
      int idx = 0;
      if (lane == 0) idx = atomicAdd(&wsi[5], 1);
      idx = __shfl(idx, 0, 64);
      const float* q1r = q0r + (size_t)Q_ * D_;
      float4 c = ((const float4*)q1r)[0];
      float4 d = ((const float4*)q1r)[1];
      float4 wa, wb;
      wa.x = fmaf(m, c.x - a.x, a.x); wa.y = fmaf(m, c.y - a.y, a.y);
      wa.z = fmaf(m, c.z - a.z, a.z); wa.w = fmaf(m, c.w - a.w, a.w);
      wb.x = fmaf(m, d.x - bb.x, bb.x); wb.y = fmaf(m, d.y - bb.y, bb.y);
      wb.z = fmaf(m, d.z - bb.z, bb.z); wb.w = fmaf(m, d.w - bb.w, bb.w);
      short8 o2;
      o2[0] = (short)f2bf(wa.x); o2[1] = (short)f2bf(wa.y);
      o2[2] = (short)f2bf(wa.z); o2[3] = (short)f2bf(wa.w);
      o2[4] = (short)f2bf(wb.x); o2[5] = (short)f2bf(wb.y);
      o2[6] = (short)f2bf(wb.z); o2[7] = (short)f2bf(wb.w);
      if (idx < MMAX) {
        *(short8*)(qmc + (size_t)idx * D_ + lane * 8) = o;   // exact bf16(q0) bits
        *(short8*)(wmc + (size_t)idx * D_ + lane * 8) = o2;
      }
    }
  } else {
    const int row = (b - Q_ / 4) * 4 + wv;
    const float* pr = p + (size_t)row * D_ + lane * 8;
    float4 a = ((const float4*)pr)[0];
    float4 bb = ((const float4*)pr)[1];
    short8 o;
    o[0] = (short)f2bf(a.x); o[1] = (short)f2bf(a.y);
    o[2] = (short)f2bf(a.z); o[3] = (short)f2bf(a.w);
    o[4] = (short)f2bf(bb.x); o[5] = (short)f2bf(bb.y);
    o[6] = (short)f2bf(bb.z); o[7] = (short)f2bf(bb.w);
    *(short8*)(pbf + (size_t)row * D_ + lane * 8) = o;
  }
}

// ---- main GEMM: single-matrix p.q0^T, Z over all cols, lists over unmasked ----
// grid (128, 8): x=split -> XCD=split%8; 1024 blocks at 3 blocks/CU.
__global__ __launch_bounds__(256, 3) void main_gemm(
    const unsigned short* __restrict__ pbf,
    const unsigned short* __restrict__ qbf0,
    const float* __restrict__ maskp,
    const int* __restrict__ label,
    char* __restrict__ ws) {
  __shared__ __align__(16) unsigned char smem[32768];
  __shared__ float Tlds[256][11];    // per-thread persistent top-10 (pad 11)
  __shared__ float maskb[NT];
  __shared__ float zacc[MT][2];
  __shared__ int olist[MT];
  __shared__ int rowmap[MT];
  __shared__ int sh_ocount;

  const int tid = threadIdx.x;
  const int split = blockIdx.x;       // 0..127
  const int mblk = blockIdx.y;        // 0..7
  const int lane = tid & 63;
  const int wv = tid >> 6;
  const int wr = wv >> 1;
  const int wc = wv & 1;
  const int lr = lane & 15;
  const int lg = lane >> 4;

  if (tid == 0) sh_ocount = 0;
  if (tid < MT) {
    rowmap[tid] = -1;
    zacc[tid][0] = 0.0f; zacc[tid][1] = 0.0f;
  }
#pragma unroll
  for (int i = 0; i < 10; ++i) Tlds[tid][i] = -1e30f;
  __syncthreads();
  if (tid < MT) {
    if (label[mblk * MT + tid] == -1) {
      int k = atomicAdd(&sh_ocount, 1);
      olist[k] = tid;
    }
  }
  __syncthreads();
  const int noc = sh_ocount;
  if (tid < noc) rowmap[olist[tid]] = tid;
  __syncthreads();
  const int nchunks = (noc + 31) >> 5;

  const int srow = lane >> 3;
  const int sc16 = (lane & 7) ^ srow;
  const size_t g_lane_off = (size_t)srow * D_ + sc16 * 8;

  for (int nt = 0; nt < NTILES; ++nt) {
    const int nbase = split * NCHUNK + nt * NT;
    if (tid < NT) maskb[tid] = maskp[nbase + tid];
    __syncthreads();   // maskb ready; prev-nt scan reads done before restaging

    f32x4 acc[4][4];
#pragma unroll
    for (int i = 0; i < 4; ++i)
#pragma unroll
      for (int j = 0; j < 4; ++j) {
        f32x4 z = {0.0f, 0.0f, 0.0f, 0.0f};
        acc[i][j] = z;
      }

    for (int kk = 0; kk < KITERS; ++kk) {
      const size_t kcol = (size_t)kk * BK;
#pragma unroll
      for (int t = 0; t < 4; ++t) {
        const int slot = wv * 4 + t;
        const size_t rbase = (size_t)slot * 8;
        async16(smem + SA_OFF + slot * 1024,
                pbf + ((size_t)mblk * MT + rbase) * D_ + kcol + g_lane_off);
        async16(smem + SB_OFF + slot * 1024,
                qbf0 + ((size_t)nbase + rbase) * D_ + kcol + g_lane_off);
      }
      __syncthreads();
#pragma unroll
      for (int s = 0; s < 2; ++s) {
        const int xs = ((s * 4 + lg) ^ (lr & 7)) * 16;
        short8 af[4], bf[4];
#pragma unroll
        for (int i = 0; i < 4; ++i)
          af[i] = *(const short8*)(smem + SA_OFF + (wr * 64 + i * 16 + lr) * 128 + xs);
#pragma unroll
        for (int j = 0; j < 4; ++j)
          bf[j] = *(const short8*)(smem + SB_OFF + (wc * 64 + j * 16 + lr) * 128 + xs);
#pragma unroll
        for (int i = 0; i < 4; ++i)
#pragma unroll
          for (int j = 0; j < 4; ++j)
            acc[i][j] = __builtin_amdgcn_mfma_f32_16x16x32_bf16(af[i], bf[j], acc[i][j], 0, 0, 0);
      }
      __syncthreads();
    }

    // ---- Z epilogue (all cols incl. masked): regs -> lr-shfl -> zacc ----
#pragma unroll
    for (int i = 0; i < 4; ++i)
#pragma unroll
      for (int k = 0; k < 4; ++k) {
        float a0 = 0.0f;
#pragma unroll
        for (int j = 0; j < 4; ++j)
          a0 += __builtin_amdgcn_exp2f(fmaf(acc[i][j][k], C32, -C32));
#pragma unroll
        for (int m = 1; m < 16; m <<= 1) a0 += __shfl_xor(a0, m, 64);
        if (lr == 0) {
          const int r = wr * 64 + i * 16 + lg * 4 + k;
          zacc[r][wc] += a0;
        }
      }

    // ---- compact outlier rows (masked cols -> -inf) + scan ----
    for (int c = 0; c < nchunks; ++c) {
      unsigned short* cp = (unsigned short*)smem;   // aliases sA
#pragma unroll
      for (int i = 0; i < 4; ++i)
#pragma unroll
        for (int k = 0; k < 4; ++k) {
          const int r = wr * 64 + i * 16 + lg * 4 + k;
          const int o = rowmap[r];
          const int ol = o - c * 32;
          if (o >= 0 && ol >= 0 && ol < 32) {
#pragma unroll
            for (int j = 0; j < 4; ++j) {
              const int col = wc * 64 + j * 16 + lr;
              unsigned short v = (maskb[col] != 0.0f) ? (unsigned short)0xFF80
                                                      : f2bf(acc[i][j][k]);
              cp[ol * CPSTRIDE + col] = v;
            }
          }
        }
      __syncthreads();

      const int orow = tid >> 3;     // 0..31
      const int q8 = tid & 7;
      const int o = c * 32 + orow;
      if (c == 0) {
        // fast path: per-thread persistent list in LDS, no per-nt merge
        if (o < noc) {
          float tl[10];
#pragma unroll
          for (int r = 0; r < 10; ++r) tl[r] = Tlds[tid][r];
          const unsigned short* rp = cp + orow * CPSTRIDE + q8 * 16;
#pragma unroll
          for (int cc = 0; cc < 4; ++cc) {
            short4v v = *(const short4v*)(rp + cc * 4);
            TKA(bf2f(v.x), tl); TKA(bf2f(v.y), tl);
            TKA(bf2f(v.z), tl); TKA(bf2f(v.w), tl);
          }
#pragma unroll
          for (int r = 0; r < 10; ++r) Tlds[tid][r] = tl[r];
        }
      } else {
        // rare overflow path (noc > 32): scan + merge + ws RMW per nt
        float tl[10];
#pragma unroll
        for (int r = 0; r < 10; ++r) tl[r] = -1e30f;
        if (o < noc) {
          const unsigned short* rp = cp + orow * CPSTRIDE + q8 * 16;
#pragma unroll
          for (int cc = 0; cc < 4; ++cc) {
            short4v v = *(const short4v*)(rp + cc * 4);
            TKA(bf2f(v.x), tl); TKA(bf2f(v.y), tl);
            TKA(bf2f(v.z), tl); TKA(bf2f(v.w), tl);
          }
        }
        float ot[10];
#pragma unroll
        for (int m = 1; m < 8; m <<= 1) {
#pragma unroll
          for (int r = 0; r < 10; ++r) ot[r] = __shfl_xor(tl[r], m, 64);
#pragma unroll
          for (int r = 0; r < 10; ++r) TKA(ot[r], tl);
        }
        if (q8 == 0 && o < noc) {
          float* slot = (float*)(ws + WS_TOPK) +
              ((size_t)(mblk * MT + olist[o]) * NSPLIT + split) * 10;
          if (nt == 0) {
#pragma unroll
            for (int r = 0; r < 10; ++r) slot[r] = tl[r];
          } else {
            float cur[10];
#pragma unroll
            for (int r = 0; r < 10; ++r) cur[r] = slot[r];
#pragma unroll
            for (int r = 0; r < 10; ++r) TKA(tl[r], cur);
#pragma unroll
            for (int r = 0; r < 10; ++r) slot[r] = cur[r];
          }
        }
      }
      __syncthreads();
    }
  }

  // ---- block end: Z partials, then merge per-thread lists across q8 ----
  if (tid < MT) {
    ((float*)(ws + WS_LSE))[(size_t)(mblk * MT + tid) * NSPLIT + split] =
        zacc[tid][0] + zacc[tid][1];
  }
  {
    const int orow = tid >> 3;
    const int q8 = tid & 7;
    float tl[10], ot[10];
#pragma unroll
    for (int r = 0; r < 10; ++r) tl[r] = Tlds[tid][r];
#pragma unroll
    for (int m = 1; m < 8; m <<= 1) {
#pragma unroll
      for (int r = 0; r < 10; ++r) ot[r] = __shfl_xor(tl[r], m, 64);
#pragma unroll
      for (int r = 0; r < 10; ++r) TKA(ot[r], tl);
    }
    if (q8 == 0 && orow < noc) {
      float* slot = (float*)(ws + WS_TOPK) +
          ((size_t)(mblk * MT + olist[orow]) * NSPLIT + split) * 10;
#pragma unroll
      for (int r = 0; r < 10; ++r) slot[r] = tl[r];
    }
  }
}

// ---- masked GEMM: p . [qmc|wmc]^T -> zdelta and masked-col top-10 lists ----
// grid (64, 8, 2): tile, mblk, half (0: q0-masked, 1: w-masked)
__global__ __launch_bounds__(256, 3) void masked_gemm(
    const unsigned short* __restrict__ pbf,
    const unsigned short* __restrict__ qmc,
    const unsigned short* __restrict__ wmc,
    const int* __restrict__ label,
    char* __restrict__ ws) {
  __shared__ __align__(16) unsigned char smem[32768];
  __shared__ float zacc[MT][2];
  __shared__ int olist[MT];
  __shared__ int rowmap[MT];
  __shared__ int sh_ocount;

  const int tid = threadIdx.x;
  const int tile = blockIdx.x;       // 0..63
  const int mblk = blockIdx.y;
  const int half = blockIdx.z;
  const int lane = tid & 63;
  const int wv = tid >> 6;
  const int wr = wv >> 1;
  const int wc = wv & 1;
  const int lr = lane & 15;
  const int lg = lane >> 4;
  const int* wsi = (const int*)ws;

  if (tid == 0) sh_ocount = 0;
  if (tid < MT) {
    rowmap[tid] = -1;
    zacc[tid][0] = 0.0f; zacc[tid][1] = 0.0f;
  }
  __syncthreads();
  if (tid < MT) {
    if (label[mblk * MT + tid] == -1) {
      int k = atomicAdd(&sh_ocount, 1);
      olist[k] = tid;
    }
  }
  __syncthreads();
  const int noc = sh_ocount;
  if (tid < noc) rowmap[olist[tid]] = tid;
  __syncthreads();
  const int nchunks = (noc + 31) >> 5;
  const int mcnt = wsi[5];

  if (tile * NT >= mcnt) {
    // inactive tile: sentinel lists for this (half, tile) so finalize can merge
    if (tid < noc) {
      float* slot = (float*)(ws + WS_TOPKM) +
          (((size_t)half * B_ + mblk * MT + olist[tid]) * MTILES + tile) * 10;
#pragma unroll
      for (int r = 0; r < 10; ++r) slot[r] = -1e30f;
    }
    return;
  }

  const unsigned short* bsrc = half ? wmc : qmc;
  const int nbase = tile * NT;
  const int srow = lane >> 3;
  const int sc16 = (lane & 7) ^ srow;
  const size_t g_lane_off = (size_t)srow * D_ + sc16 * 8;

  f32x4 acc[4][4];
#pragma unroll
  for (int i = 0; i < 4; ++i)
#pragma unroll
    for (int j = 0; j < 4; ++j) {
      f32x4 z = {0.0f, 0.0f, 0.0f, 0.0f};
      acc[i][j] = z;
    }

  for (int kk = 0; kk < KITERS; ++kk) {
    const size_t kcol = (size_t)kk * BK;
#pragma unroll
    for (int t = 0; t < 4; ++t) {
      const int slot = wv * 4 + t;
      const size_t rbase = (size_t)slot * 8;
      async16(smem + SA_OFF + slot * 1024,
              pbf + ((size_t)mblk * MT + rbase) * D_ + kcol + g_lane_off);
      async16(smem + SB_OFF + slot * 1024,
              bsrc + ((size_t)nbase + rbase) * D_ + kcol + g_lane_off);
    }
    __syncthreads();
#pragma unroll
    for (int s = 0; s < 2; ++s) {
      const int xs = ((s * 4 + lg) ^ (lr & 7)) * 16;
      short8 af[4], bf[4];
#pragma unroll
      for (int i = 0; i < 4; ++i)
        af[i] = *(const short8*)(smem + SA_OFF + (wr * 64 + i * 16 + lr) * 128 + xs);
#pragma unroll
      for (int j = 0; j < 4; ++j)
        bf[j] = *(const short8*)(smem + SB_OFF + (wc * 64 + j * 16 + lr) * 128 + xs);
#pragma unroll
      for (int i = 0; i < 4; ++i)
#pragma unroll
        for (int j = 0; j < 4; ++j)
          acc[i][j] = __builtin_amdgcn_mfma_f32_16x16x32_bf16(af[i], bf[j], acc[i][j], 0, 0, 0);
    }
    __syncthreads();
  }

  // Z sums over this tile's cols (zero-pad cols add ~2^-46, negligible)
#pragma unroll
  for (int i = 0; i < 4; ++i)
#pragma unroll
    for (int k = 0; k < 4; ++k) {
      float a0 = 0.0f;
#pragma unroll
      for (int j = 0; j < 4; ++j)
        a0 += __builtin_amdgcn_exp2f(fmaf(acc[i][j][k], C32, -C32));
#pragma unroll
      for (int m = 1; m < 16; m <<= 1) a0 += __shfl_xor(a0, m, 64);
      if (lr == 0) {
        const int r = wr * 64 + i * 16 + lg * 4 + k;
        zacc[r][wc] += a0;
      }
    }
  __syncthreads();
  if (tid < MT) {
    float z = zacc[tid][0] + zacc[tid][1];
    atomicAdd((float*)(ws + WS_ZDELTA) + (mblk * MT + tid), half ? z : -z);
  }

  // compact + scan + merge + write (single pass; no exclusion)
  for (int c = 0; c < nchunks; ++c) {
    unsigned short* cp = (unsigned short*)smem;
#pragma unroll
    for (int i = 0; i < 4; ++i)
#pragma unroll
      for (int k = 0; k < 4; ++k) {
        const int r = wr * 64 + i * 16 + lg * 4 + k;
        const int o = rowmap[r];
        const int ol = o - c * 32;
        if (o >= 0 && ol >= 0 && ol < 32) {
#pragma unroll
          for (int j = 0; j < 4; ++j) {
            const int col = wc * 64 + j * 16 + lr;
            cp[ol * CPSTRIDE + col] = f2bf(acc[i][j][k]);
          }
        }
      }
    __syncthreads();
    const int orow = tid >> 3;
    const int q8 = tid & 7;
    const int o = c * 32 + orow;
    float tl[10], ot[10];
#pragma unroll
    for (int r = 0; r < 10; ++r) tl[r] = -1e30f;
    if (o < noc) {
      const unsigned short* rp = cp + orow * CPSTRIDE + q8 * 16;
#pragma unroll
      for (int cc = 0; cc < 4; ++cc) {
        short4v v = *(const short4v*)(rp + cc * 4);
        TKA(bf2f(v.x), tl); TKA(bf2f(v.y), tl);
        TKA(bf2f(v.z), tl); TKA(bf2f(v.w), tl);
      }
    }
#pragma unroll
    for (int m = 1; m < 8; m <<= 1) {
#pragma unroll
      for (int r = 0; r < 10; ++r) ot[r] = __shfl_xor(tl[r], m, 64);
#pragma unroll
      for (int r = 0; r < 10; ++r) TKA(ot[r], tl);
    }
    if (q8 == 0 && o < noc) {
      float* slot = (float*)(ws + WS_TOPKM) +
          (((size_t)half * B_ + mblk * MT + olist[o]) * MTILES + tile) * 10;
#pragma unroll
      for (int r = 0; r < 10; ++r) slot[r] = tl[r];
    }
    __syncthreads();
  }
}

__global__ void finalize_rows(
    const float* __restrict__ p, const float* __restrict__ queue,
    const float* __restrict__ maskp, const int* __restrict__ label,
    char* __restrict__ ws, float* __restrict__ out) {
  const int row = blockIdx.x;
  const int l = threadIdx.x >> 6;     // 0: cos1 loss, 1: cos2 loss
  const int lane = threadIdx.x & 63;
  const int lab = label[row];
  float* wsf = (float*)ws;
  int* wsi = (int*)ws;

  if (lab != -1) {
    // ---- Z = sum of 128 main partials (+ zdelta for cos2) ----
    const float* lsep = (const float*)(ws + WS_LSE) + (size_t)row * NSPLIT;
    float z = lsep[lane] + lsep[lane + 64];
#pragma unroll
    for (int o = 1; o < 64; o <<= 1) z += __shfl_xor(z, o, 64);
    if (l == 1) z += ((const float*)(ws + WS_ZDELTA))[row];

    // ---- exact fp32 gt dot(s) ----
    const float* prow = p + (size_t)row * D_;
    const float* q0r = queue + (size_t)lab * D_;
    const float* q1r = queue + ((size_t)Q_ + (size_t)lab) * D_;
    int c = lane * 8;
    float4 a0 = *(const float4*)(prow + c);
    float4 a1 = *(const float4*)(prow + c + 4);
    float4 b0 = *(const float4*)(q0r + c);
    float4 b1 = *(const float4*)(q0r + c + 4);
    float d0 = a0.x * b0.x + a0.y * b0.y + a0.z * b0.z + a0.w * b0.w
             + a1.x * b1.x + a1.y * b1.y + a1.z * b1.z + a1.w * b1.w;
    float d1 = 0.0f;
    if (l == 1) {
      float4 c0 = *(const float4*)(q1r + c);
      float4 c1 = *(const float4*)(q1r + c + 4);
      d1 = a0.x * c0.x + a0.y * c0.y + a0.z * c0.z + a0.w * c0.w
         + a1.x * c1.x + a1.y * c1.y + a1.z * c1.z + a1.w * c1.w;
    }
#pragma unroll
    for (int o = 1; o < 64; o <<= 1) {
      d0 += __shfl_xor(d0, o, 64);
      d1 += __shfl_xor(d1, o, 64);
    }
    float gt;
    if (l == 0) gt = d0;
    else { float m = maskp[lab]; gt = fmaf(m, d1 - d0, d0); }

    if (lane == 0) {
      float e1 = __builtin_amdgcn_exp2f(fmaf(gt, C32, -C32));
      float e2 = __builtin_amdgcn_exp2f(fmaf(gt - 0.4f, C32, -C32));
      float Zc = z - e1 + e2;
      float ce = 32.0f + __logf(Zc) - (gt - 0.4f) * SCALE32;
      atomicAdd(&wsf[0], ce);
      if (l == 0) atomicAdd(&wsi[2], 1);
    }
  } else {
    // ---- merge 128 main (unmasked) + 64 masked-half lists, tournament ----
    const float* Lm1 = (const float*)(ws + WS_TOPK) + ((size_t)row * NSPLIT + lane) * 10;
    const float* Lm2 = (const float*)(ws + WS_TOPK) + ((size_t)row * NSPLIT + 64 + lane) * 10;
    const float* Lk  = (const float*)(ws + WS_TOPKM) +
                       (((size_t)l * B_ + row) * MTILES + lane) * 10;
    float t0 = Lm1[0], t1 = Lm1[1], t2 = Lm1[2], t3 = Lm1[3], t4 = Lm1[4];
    float t5 = Lm1[5], t6 = Lm1[6], t7 = Lm1[7], t8 = Lm1[8], t9 = Lm1[9];
#pragma unroll
    for (int i = 0; i < 10; ++i)
      tkins(Lm2[i], t0, t1, t2, t3, t4, t5, t6, t7, t8, t9);
#pragma unroll
    for (int i = 0; i < 10; ++i)
      tkins(Lk[i], t0, t1, t2, t3, t4, t5, t6, t7, t8, t9);
    float ssum = 0.0f;
#pragma unroll
    for (int r10 = 0; r10 < 10; ++r10) {
      float v = t0;
      int idx = lane;
#pragma unroll
      for (int o = 1; o < 64; o <<= 1) {
        float ov = __shfl_xor(v, o, 64);
        int oi = __shfl_xor(idx, o, 64);
        bool take = (ov > v) || (ov == v && oi < idx);
        v = take ? ov : v;
        idx = take ? oi : idx;
      }
      ssum += fmaxf(v, 0.0f);
      if (idx == lane) {
        t0 = t1; t1 = t2; t2 = t3; t3 = t4; t4 = t5;
        t5 = t6; t6 = t7; t7 = t8; t8 = t9; t9 = -1e30f;
      }
    }
    if (lane == 0) {
      atomicAdd(&wsf[1], ssum * 0.1f);
      if (l == 0) atomicAdd(&wsi[3], 1);
    }
  }

  // ---- last block writes the final scalar ----
  __syncthreads();
  if (threadIdx.x == 0) {
    __threadfence();
    int old = atomicAdd(&wsi[4], 1);
    if (old == B_ - 1) {
      float ce = atomicAdd(&wsf[0], 0.0f);
      float ng = atomicAdd(&wsf[1], 0.0f);
      int np = atomicAdd(&wsi[2], 0);
      int nn = atomicAdd(&wsi[3], 0);
      float loss = 0.0f;
      if (np > 0) loss += ce / (float)np;
      if (nn > 0) loss += ng / (float)nn;
      out[0] = loss;
    }
  }
}

extern "C" void kernel_launch(void* const* d_in, const int* in_sizes, int n_in,
                              void* d_out, int out_size, void* d_ws, size_t ws_size,
                              hipStream_t stream) {
  const float* p     = (const float*)d_in[0];
  const float* queue = (const float*)d_in[1];
  const float* maskp = (const float*)d_in[2];
  const int*   label = (const int*)d_in[3];
  float* out = (float*)d_out;
  char* ws = (char*)d_ws;

  unsigned short* pbf  = (unsigned short*)(ws + WS_PBF);
  unsigned short* qbf0 = (unsigned short*)(ws + WS_QBF0);
  unsigned short* qmc  = (unsigned short*)(ws + WS_QMC);
  unsigned short* wmc  = (unsigned short*)(ws + WS_WMC);

  // zero accumulators + mcnt + zdelta, and the padded compact arrays
  hipMemsetAsync(ws, 0, WS_ZDELTA + B_ * 4, stream);
  hipMemsetAsync(ws + WS_QMC, 0, 2u * MMAX * D_ * 2u, stream);

  cvt_all<<<Q_ / 4 + B_ / 4, 256, 0, stream>>>(queue, p, maskp, qbf0, pbf,
                                               qmc, wmc, (int*)ws);

  masked_gemm<<<dim3(MTILES, B_ / MT, 2), 256, 0, stream>>>(pbf, qmc, wmc, label, ws);
  main_gemm<<<dim3(NSPLIT, B_ / MT), 256, 0, stream>>>(pbf, qbf0, maskp, label, ws);
  finalize_rows<<<B_, 128, 0, stream>>>(p, queue, maskp, label, ws, out);
}